// Round 8
// baseline (1077.676 us; speedup 1.0000x reference)
//
#include <hip/hip_runtime.h>
#include <math.h>

constexpr int cB = 128, cS = 256, cF = 10, cE = 40, cNH = 8, cDH = 5;
constexpr int cI = 128, cMDH = 16, cK = 4;

// broadcast lane (group_base + l) to all 8 lanes of the group (groups of 8 within 32-lane halves)
#define BC8(v, l) __uint_as_float(__builtin_amdgcn_ds_swizzle(__float_as_uint(v), ((l) << 5) | 0x18))

// ---------------- h = x @ in_w.T + in_b + pos_encoding ----------------
__global__ __launch_bounds__(256) void init_k(const float* __restrict__ x, const float* __restrict__ w,
                                              const float* __restrict__ b, float* __restrict__ h) {
    int idx = blockIdx.x * 256 + threadIdx.x;     // B*S*E
    int e = idx % cE; int bs = idx / cE; int s = bs % cS;
    float acc = b[e];
    const float* xr = x + (size_t)bs * cF;
#pragma unroll
    for (int f = 0; f < cF; ++f) acc += xr[f] * w[e * cF + f];
    int i2 = e >> 1;
    float div = expf(-(float)(2 * i2) * (logf(10000.f) / 40.0f));
    float arg = (float)s * div;
    acc += (e & 1) ? cosf(arg) : sinf(arg);
    h[idx] = acc;
}

// ---------------- fused LayerNorm + up-projection (E=40 -> 256) ----------------
__global__ __launch_bounds__(256) void ln_up_k(const float* __restrict__ h, const float* __restrict__ lnw,
                                               const float* __restrict__ upw, float* __restrict__ xmz) {
    __shared__ float lnr[8][cE];
    int row0 = blockIdx.x * 8;
    int tid = threadIdx.x;
    if (tid < 8) {
        const float* r = h + (size_t)(row0 + tid) * cE;
        float mu = 0.f;
        for (int k = 0; k < cE; ++k) mu += r[k];
        mu *= (1.f / cE);
        float va = 0.f;
        for (int k = 0; k < cE; ++k) { float d = r[k] - mu; va += d * d; }
        va *= (1.f / cE);
        float rs = rsqrtf(va + 1e-5f);
        for (int k = 0; k < cE; ++k) lnr[tid][k] = (r[k] - mu) * rs * lnw[k];
    }
    __syncthreads();
    int o = tid;   // 0..255
    float acc[8] = {0, 0, 0, 0, 0, 0, 0, 0};
    for (int k = 0; k < cE; ++k) {
        float wv = upw[o * cE + k];
#pragma unroll
        for (int r = 0; r < 8; ++r) acc[r] += lnr[r][k] * wv;
    }
#pragma unroll
    for (int r = 0; r < 8; ++r) xmz[(size_t)(row0 + r) * 256 + o] = acc[r];
}

// ---------------- depthwise causal conv (K=4) + SiLU ----------------
template <int C>
__global__ __launch_bounds__(256) void conv_silu_k(const float* __restrict__ in, int instride,
                                                   const float* __restrict__ w, const float* __restrict__ bias,
                                                   float* __restrict__ out) {
    int idx = blockIdx.x * 256 + threadIdx.x;   // B*S*C
    int c = idx % C; int bs = idx / C; int s = bs % cS;
    float acc = bias[c];
#pragma unroll
    for (int j = 0; j < cK; ++j) {
        int sj = s - 3 + j;
        if (sj >= 0) acc += in[(size_t)(bs + j - 3) * instride + c] * w[c * cK + j];
    }
    float sg = 1.f / (1.f + __expf(-acc));
    out[idx] = acc * sg;
}

// ---------------- block-diagonal headwise q,k,v ----------------
__global__ __launch_bounds__(256) void qkv_k(const float* __restrict__ xc, const float* __restrict__ xmz,
                                             const float* __restrict__ qw, const float* __restrict__ kw,
                                             const float* __restrict__ vw,
                                             float* __restrict__ qb, float* __restrict__ kb, float* __restrict__ vb) {
    int idx = blockIdx.x * 256 + threadIdx.x;   // B*S*I
    int c = idx & 127; int bs = idx >> 7;
    int n = c >> 2, o = c & 3;
    const float* xcr = xc + (size_t)bs * cI + n * 4;
    const float* xmr = xmz + (size_t)bs * 256 + n * 4;
    const float* qwp = qw + n * 16 + o * 4;
    const float* kwp = kw + n * 16 + o * 4;
    const float* vwp = vw + n * 16 + o * 4;
    float aq = 0, ak = 0, av = 0;
#pragma unroll
    for (int i = 0; i < 4; ++i) { float a = xcr[i], m = xmr[i]; aq += a * qwp[i]; ak += a * kwp[i]; av += m * vwp[i]; }
    qb[idx] = aq; kb[idx] = ak; vb[idx] = av;
}

// ---------------- input/forget gate pre-activations ip, fp (B,NH,S) v2 ----------------
__global__ __launch_bounds__(128, 2) void gates_k(const float* __restrict__ qb, const float* __restrict__ kb,
                                                  const float* __restrict__ vb, const float* __restrict__ igw,
                                                  const float* __restrict__ igb, const float* __restrict__ fgw,
                                                  const float* __restrict__ fgb,
                                                  float* __restrict__ ipb, float* __restrict__ fpb) {
    __shared__ float g[32 * 388];
    __shared__ float w[16 * 388];
    int row0 = blockIdx.x * 32;
    int tid = threadIdx.x;

    for (int i = tid; i < 16 * 96; i += 128) {
        int r = i / 96, c4 = i - r * 96;
        const float* src = (r < 8) ? (igw + r * 384) : (fgw + (r - 8) * 384);
        *(float4*)&w[r * 388 + c4 * 4] = ((const float4*)src)[c4];
    }
    for (int i = tid; i < 32 * 96; i += 128) {
        int r = i / 96, c4 = i - r * 96;
        size_t gr = (size_t)(row0 + r) * cI;
        const float4* src = (c4 < 32) ? (const float4*)(qb + gr) + c4
                          : (c4 < 64) ? (const float4*)(kb + gr) + (c4 - 32)
                                      : (const float4*)(vb + gr) + (c4 - 64);
        *(float4*)&g[r * 388 + c4 * 4] = *src;
    }
    __syncthreads();

    int rp = tid >> 3;
    int hp = tid & 7;
    int r0 = 2 * rp, r1 = r0 + 1;
    int o0 = 2 * hp, o1 = o0 + 1;

    const float4* g0p = (const float4*)(g + r0 * 388);
    const float4* g1p = (const float4*)(g + r1 * 388);
    const float4* w0p = (const float4*)(w + o0 * 388);
    const float4* w1p = (const float4*)(w + o1 * 388);

    float a00 = 0.f, a01 = 0.f, a10 = 0.f, a11 = 0.f;
#pragma unroll 4
    for (int c4 = 0; c4 < 96; ++c4) {
        float4 gv0 = g0p[c4], gv1 = g1p[c4];
        float4 wv0 = w0p[c4], wv1 = w1p[c4];
        a00 = fmaf(gv0.x, wv0.x, a00); a00 = fmaf(gv0.y, wv0.y, a00);
        a00 = fmaf(gv0.z, wv0.z, a00); a00 = fmaf(gv0.w, wv0.w, a00);
        a01 = fmaf(gv0.x, wv1.x, a01); a01 = fmaf(gv0.y, wv1.y, a01);
        a01 = fmaf(gv0.z, wv1.z, a01); a01 = fmaf(gv0.w, wv1.w, a01);
        a10 = fmaf(gv1.x, wv0.x, a10); a10 = fmaf(gv1.y, wv0.y, a10);
        a10 = fmaf(gv1.z, wv0.z, a10); a10 = fmaf(gv1.w, wv0.w, a10);
        a11 = fmaf(gv1.x, wv1.x, a11); a11 = fmaf(gv1.y, wv1.y, a11);
        a11 = fmaf(gv1.z, wv1.z, a11); a11 = fmaf(gv1.w, wv1.w, a11);
    }

    int h0 = o0 & 7, wch0 = o0 >> 3;
    int h1 = o1 & 7, wch1 = o1 >> 3;
    float b0 = wch0 ? fgb[h0] : igb[h0];
    float b1 = wch1 ? fgb[h1] : igb[h1];
    int grow0 = row0 + r0, grow1 = row0 + r1;
    int bb0 = grow0 >> 8, ss0 = grow0 & 255;
    int bb1 = grow1 >> 8, ss1 = grow1 & 255;
    float* d00 = (wch0 ? fpb : ipb) + (size_t)(bb0 * cNH + h0) * cS + ss0;
    float* d01 = (wch1 ? fpb : ipb) + (size_t)(bb0 * cNH + h1) * cS + ss0;
    float* d10 = (wch0 ? fpb : ipb) + (size_t)(bb1 * cNH + h0) * cS + ss1;
    float* d11 = (wch1 ? fpb : ipb) + (size_t)(bb1 * cNH + h1) * cS + ss1;
    *d00 = a00 + b0; *d01 = a01 + b1; *d10 = a10 + b0; *d11 = a11 + b1;
}

// ---------------- fused mLSTM attention v4 ----------------
// 2 waves per (b,h), interleaved 32-t-chunks. New vs v3: exp factorized out of
// the hot loop (wgt = sEA[t] * eMx[r], one mul instead of sub+trans-exp) and
// 4-way qk dot tree (chain 64->20cy). |at| <= ~35 so exp(at) <= e^35: no overflow.
__global__ __launch_bounds__(128, 2) void attn_k(const float* __restrict__ qg, const float* __restrict__ kg,
                                                 const float* __restrict__ vg, const float* __restrict__ ipg,
                                                 const float* __restrict__ fpg, float* __restrict__ hatt) {
    int bh = blockIdx.x; int b = bh >> 3, h = bh & 7;
    int tid = threadIdx.x;
    int wid = tid >> 6, lane = tid & 63;
    __shared__ float sEA[cS], sMx[cS], sFc[cS];
    __shared__ float sKf[cS * cMDH], sVf[cS * cMDH];

    const float4 fp4 = ((const float4*)(fpg + (size_t)bh * cS))[lane];
    const float4 ip4 = ((const float4*)(ipg + (size_t)bh * cS))[lane];
    float fpa[4] = {fp4.x, fp4.y, fp4.z, fp4.w};
    float ipa[4] = {ip4.x, ip4.y, ip4.z, ip4.w};
    float p[4];
    {
        float run = 0.f;
#pragma unroll
        for (int i = 0; i < 4; ++i) {
            float xx = fpa[i];
            float lsg = fminf(xx, 0.f) - log1pf(expf(-fabsf(xx)));
            run += lsg; p[i] = run;
        }
    }
    float cum = p[3];
#pragma unroll
    for (int off = 1; off < 64; off <<= 1) { float t = __shfl_up(cum, off); if (lane >= off) cum += t; }
    float excl = cum - p[3];
    float aa[4];
#pragma unroll
    for (int i = 0; i < 4; ++i) {
        float fcv = excl + p[i];
        aa[i] = ipa[i] - fcv;
        sFc[lane * 4 + i] = fcv;
        sEA[lane * 4 + i] = __expf(aa[i]);    // exp(a[t]) precomputed once per t
    }
    float mq[4]; mq[0] = aa[0];
#pragma unroll
    for (int i = 1; i < 4; ++i) mq[i] = fmaxf(mq[i - 1], aa[i]);
    float cm = mq[3];
#pragma unroll
    for (int off = 1; off < 64; off <<= 1) { float t = __shfl_up(cm, off); if (lane >= off) cm = fmaxf(cm, t); }
    float exm = __shfl_up(cm, 1);
    if (lane == 0) exm = -3.0e38f;
#pragma unroll
    for (int i = 0; i < 4; ++i) sMx[lane * 4 + i] = fmaxf(exm, mq[i]);

#pragma unroll
    for (int rr = 0; rr < 2; ++rr) {
        int t = tid + 128 * rr;
        const float4* kp = (const float4*)(kg + ((size_t)(b * cS) + t) * cI + h * cMDH);
        const float4* vp = (const float4*)(vg + ((size_t)(b * cS) + t) * cI + h * cMDH);
        float4* kd = (float4*)(sKf + t * cMDH);
        float4* vd = (float4*)(sVf + t * cMDH);
#pragma unroll
        for (int j = 0; j < 4; ++j) { kd[j] = kp[j]; vd[j] = vp[j]; }
    }
    float qreg[4][16];
#pragma unroll
    for (int r = 0; r < 4; ++r) {
        int s = lane + 64 * r;
        const float4* qp = (const float4*)(qg + ((size_t)(b * cS) + s) * cI + h * cMDH);
#pragma unroll
        for (int j = 0; j < 4; ++j) {
            float4 t4 = qp[j];
            qreg[r][4 * j] = t4.x; qreg[r][4 * j + 1] = t4.y; qreg[r][4 * j + 2] = t4.z; qreg[r][4 * j + 3] = t4.w;
        }
    }
    __syncthreads();

    float MxR[4], flr[4], eMx[4];
#pragma unroll
    for (int r = 0; r < 4; ++r) {
        int s = lane + 64 * r;
        MxR[r] = sMx[s];
        flr[r] = __expf(-(sFc[s] + MxR[r]));
        eMx[r] = __expf(-MxR[r]);
    }
    float acc[4][16];
#pragma unroll
    for (int r = 0; r < 4; ++r)
#pragma unroll
        for (int d = 0; d < 16; ++d) acc[r][d] = 0.f;
    float sumC[4] = {0, 0, 0, 0};

    for (int ch = wid; ch < 8; ch += 2) {
        int t0 = ch * 32;
#pragma unroll 2
        for (int t = t0; t < t0 + 32; ++t) {
            float ea = sEA[t];
            float kv[16], vv[16];
#pragma unroll
            for (int j = 0; j < 4; ++j) {
                float4 t4 = ((const float4*)(sKf + t * cMDH))[j];
                kv[4 * j] = t4.x; kv[4 * j + 1] = t4.y; kv[4 * j + 2] = t4.z; kv[4 * j + 3] = t4.w;
                float4 u4 = ((const float4*)(sVf + t * cMDH))[j];
                vv[4 * j] = u4.x; vv[4 * j + 1] = u4.y; vv[4 * j + 2] = u4.z; vv[4 * j + 3] = u4.w;
            }
#pragma unroll
            for (int r = 0; r < 4; ++r) {
                if (t0 <= 63 + 64 * r) {
                    if (t <= lane + 64 * r) {
                        float wgt = ea * eMx[r];   // exp(a[t]-Mx[s]) factorized
                        float d0 = fmaf(qreg[r][0], kv[0], fmaf(qreg[r][1], kv[1], fmaf(qreg[r][2], kv[2], qreg[r][3] * kv[3])));
                        float d1 = fmaf(qreg[r][4], kv[4], fmaf(qreg[r][5], kv[5], fmaf(qreg[r][6], kv[6], qreg[r][7] * kv[7])));
                        float d2 = fmaf(qreg[r][8], kv[8], fmaf(qreg[r][9], kv[9], fmaf(qreg[r][10], kv[10], qreg[r][11] * kv[11])));
                        float d3 = fmaf(qreg[r][12], kv[12], fmaf(qreg[r][13], kv[13], fmaf(qreg[r][14], kv[14], qreg[r][15] * kv[15])));
                        float qk = (d0 + d1) + (d2 + d3);
                        float ccf = qk * 0.25f * wgt;
                        sumC[r] += ccf;
#pragma unroll
                        for (int d = 0; d < 16; ++d) acc[r][d] += ccf * vv[d];
                    }
                }
            }
        }
    }

    __syncthreads();
    if (wid == 1) {
#pragma unroll
        for (int r = 0; r < 4; ++r) {
            float4* dst = (float4*)sKf + ((size_t)(r * 64 + lane)) * 4;
#pragma unroll
            for (int j = 0; j < 4; ++j)
                dst[j] = make_float4(acc[r][4 * j], acc[r][4 * j + 1], acc[r][4 * j + 2], acc[r][4 * j + 3]);
            sMx[r * 64 + lane] = sumC[r];
        }
    }
    __syncthreads();
    if (wid == 0) {
#pragma unroll
        for (int r = 0; r < 4; ++r) {
            int s = lane + 64 * r;
            const float4* pa = (const float4*)sKf + ((size_t)(r * 64 + lane)) * 4;
            float sC = sumC[r] + sMx[r * 64 + lane];
            float nrm = fmaxf(fabsf(sC), flr[r]) + 1e-6f;
            float inv = 1.f / nrm;
            float4* op = (float4*)(hatt + ((size_t)(b * cS) + s) * cI + h * cMDH);
#pragma unroll
            for (int j = 0; j < 4; ++j) {
                float4 w1 = pa[j];
                op[j] = make_float4((acc[r][4 * j] + w1.x) * inv, (acc[r][4 * j + 1] + w1.y) * inv,
                                    (acc[r][4 * j + 2] + w1.z) * inv, (acc[r][4 * j + 3] + w1.w) * inv);
            }
        }
    }
}

// ---------------- multihead-norm + skip*x_c, gated by silu(z); in-place on hatt ----------------
__global__ __launch_bounds__(256) void mhn_y_k(float* __restrict__ hatt, const float* __restrict__ xc,
                                               const float* __restrict__ xmz, const float* __restrict__ mhnw,
                                               const float* __restrict__ skip) {
    int idx = blockIdx.x * 256 + threadIdx.x;   // B*S*NH
    int h = idx & 7; int row = idx >> 3;
    float* hp = hatt + (size_t)row * cI + h * cMDH;
    float xv[16];
#pragma unroll
    for (int d = 0; d < 16; ++d) xv[d] = hp[d];
    float mu = 0;
#pragma unroll
    for (int d = 0; d < 16; ++d) mu += xv[d];
    mu *= (1.f / 16);
    float va = 0;
#pragma unroll
    for (int d = 0; d < 16; ++d) { float dd = xv[d] - mu; va += dd * dd; }
    va *= (1.f / 16);
    float rs = rsqrtf(va + 1e-5f);
#pragma unroll
    for (int d = 0; d < 16; ++d) {
        int i = h * cMDH + d;
        float z = xmz[(size_t)row * 256 + 128 + i];
        float sg = 1.f / (1.f + __expf(-z));
        hp[d] = ((xv[d] - mu) * rs * mhnw[i] + skip[i] * xc[(size_t)row * cI + i]) * (z * sg);
    }
}

// ---------------- down-projection (128 -> 40) + residual into h ----------------
__global__ __launch_bounds__(320) void down_res_k(const float* __restrict__ y, const float* __restrict__ dw,
                                                  float* __restrict__ h) {
    __shared__ float yl[8 * 128];
    int row0 = blockIdx.x * 8;
    for (int i = threadIdx.x; i < 1024; i += 320) yl[i] = y[(size_t)row0 * cI + i];
    __syncthreads();
    int r = threadIdx.x / 40, e = threadIdx.x % 40;
    const float* dr = dw + e * cI;
    const float* yr = yl + r * cI;
    float acc = 0.f;
    for (int i = 0; i < cI; ++i) acc += yr[i] * dr[i];
    h[(size_t)(row0 + r) * cE + e] += acc;
}

// ---------------- plain row LayerNorm (E=40) ----------------
__global__ __launch_bounds__(256) void ln_rows_k(const float* __restrict__ h, const float* __restrict__ w,
                                                 float* __restrict__ out) {
    int rid = blockIdx.x * 256 + threadIdx.x;
    const float* r = h + (size_t)rid * cE;
    float mu = 0;
    for (int k = 0; k < cE; ++k) mu += r[k];
    mu *= (1.f / cE);
    float va = 0;
    for (int k = 0; k < cE; ++k) { float d = r[k] - mu; va += d * d; }
    va *= (1.f / cE);
    float rs = rsqrtf(va + 1e-5f);
    float* o = out + (size_t)rid * cE;
    for (int k = 0; k < cE; ++k) o[k] = (r[k] - mu) * rs * w[k];
}

// ---------------- sLSTM gate pre-activations; gall layout (S, B*NH, E=5, G=4) ----------------
__global__ __launch_bounds__(256) void sgates_k(const float* __restrict__ xcs, const float* __restrict__ ln1,
                                                const float* __restrict__ wi, const float* __restrict__ wf,
                                                const float* __restrict__ wz, const float* __restrict__ wo,
                                                float* __restrict__ gall) {
    int idx = blockIdx.x * 256 + threadIdx.x;   // S*1024*5*4
    int g = idx & 3; int r1 = idx >> 2;
    int e = r1 % 5; int r2 = r1 / 5;
    int bh = r2 & 1023; int s = r2 >> 10;
    int b = bh >> 3, h = bh & 7;
    const float* in = (g < 2) ? xcs : ln1;
    const float* w = (g == 0) ? wi : (g == 1) ? wf : (g == 2) ? wz : wo;
    const float* ir = in + ((size_t)(b * cS) + s) * cE + h * cDH;
    const float* wp = w + h * 25 + e * 5;
    float acc = 0.f;
#pragma unroll
    for (int i = 0; i < 5; ++i) acc += ir[i] * wp[i];
    gall[idx] = acc;
}

// ---------------- sLSTM sequential scan v3: 2 chain-sets per wave ----------------
// Wave owns 16 chains: set A = blk*16+grp, set B = A+8 (same h -> shared R/bias
// registers). A-step and B-step are independent; interleaving them fills the
// swizzle/trans/vmcnt latency of one with the other's issue. Direct per-step
// global writes with prefetched h_old (no LDS, no barriers). 64 blocks.
__global__ __launch_bounds__(64) void scan_k(const float* __restrict__ gall, const float* __restrict__ R,
                                             const float* __restrict__ bias, const float* __restrict__ mhnw,
                                             float* __restrict__ hbuf) {
    int lane = threadIdx.x;
    int grp = lane >> 3;                 // 0..7  == head h
    int e = lane & 7;                    // 0..4 active, 5..7 clone e=4
    int ee = e < 5 ? e : 4;
    int h = grp;
    int bhA = blockIdx.x * 16 + grp;     // b = 2*blk
    // bhB = bhA + 8                     // b = 2*blk+1, same h

    float Rr[4][5];
#pragma unroll
    for (int g = 0; g < 4; ++g)
#pragma unroll
        for (int d = 0; d < 5; ++d) Rr[g][d] = R[h * 100 + g * 25 + d * 5 + ee];
    float bg[4];
#pragma unroll
    for (int g = 0; g < 4; ++g) bg[g] = bias[h * 20 + g * 5 + ee];
    float wmh = mhnw[h * 5 + ee];

    const float4* gpA = (const float4*)gall + ((size_t)bhA * 5 + ee);
    const float4* gpB = gpA + 40;        // (bhA+8)*5 = +40 float4s
    float* hbA = hbuf + (size_t)(2 * blockIdx.x) * cS * cE + h * cDH + ee;
    float* hbB = hbA + (size_t)cS * cE;

    float4 rgA[4], rgB[4];
    float rhA[4], rhB[4];
#pragma unroll
    for (int j = 0; j < 4; ++j) {
        rgA[j] = gpA[(size_t)j * 5120]; rhA[j] = hbA[(size_t)j * 40];
        rgB[j] = gpB[(size_t)j * 5120]; rhB[j] = hbB[(size_t)j * 40];
    }

    float cA = 0.f, nA = 0.f, mA = 0.f, a0 = 0.f, a1 = 0.f, a2 = 0.f, a3 = 0.f, a4 = 0.f;
    float cB = 0.f, nB = 0.f, mB = 0.f, b0 = 0.f, b1 = 0.f, b2 = 0.f, b3 = 0.f, b4 = 0.f;

    auto step = [&](float4 g4, float hold, float* dst,
                    float& cs, float& ns, float& ms,
                    float& s0, float& s1, float& s2, float& s3, float& s4) {
        float ir = g4.x + bg[0], fr = g4.y + bg[1], zr = g4.z + bg[2], orr = g4.w + bg[3];
        ir = fmaf(s0, Rr[0][0], ir); fr = fmaf(s0, Rr[1][0], fr);
        zr = fmaf(s0, Rr[2][0], zr); orr = fmaf(s0, Rr[3][0], orr);
        ir = fmaf(s1, Rr[0][1], ir); fr = fmaf(s1, Rr[1][1], fr);
        zr = fmaf(s1, Rr[2][1], zr); orr = fmaf(s1, Rr[3][1], orr);
        ir = fmaf(s2, Rr[0][2], ir); fr = fmaf(s2, Rr[1][2], fr);
        zr = fmaf(s2, Rr[2][2], zr); orr = fmaf(s2, Rr[3][2], orr);
        ir = fmaf(s3, Rr[0][3], ir); fr = fmaf(s3, Rr[1][3], fr);
        zr = fmaf(s3, Rr[2][3], zr); orr = fmaf(s3, Rr[3][3], orr);
        ir = fmaf(s4, Rr[0][4], ir); fr = fmaf(s4, Rr[1][4], fr);
        zr = fmaf(s4, Rr[2][4], zr); orr = fmaf(s4, Rr[3][4], orr);

        float lsg = fminf(fr, 0.f) - __logf(1.f + __expf(-fabsf(fr)));
        float lfm = ms + lsg;
        float mn = fmaxf(ir, lfm);
        float ig = __expf(ir - mn), fg = __expf(lfm - mn);
        float th = 1.f - 2.f * __builtin_amdgcn_rcpf(__expf(2.f * zr) + 1.f);
        float cn = fg * cs + ig * th;
        float nn = fg * ns + ig;
        float sg = __builtin_amdgcn_rcpf(1.f + __expf(-orr));
        float hn = sg * cn * __builtin_amdgcn_rcpf(nn);
        cs = cn; ns = nn; ms = mn;

        s0 = BC8(hn, 0); s1 = BC8(hn, 1); s2 = BC8(hn, 2);
        s3 = BC8(hn, 3); s4 = BC8(hn, 4);
        float mu = ((s0 + s1) + (s2 + s3) + s4) * 0.2f;
        float d0 = s0 - mu, d1 = s1 - mu, d2 = s2 - mu, d3 = s3 - mu, d4 = s4 - mu;
        float va = (d0 * d0 + d1 * d1 + d2 * d2 + d3 * d3 + d4 * d4) * 0.2f;
        float rs = __builtin_amdgcn_rsqf(va + 1e-5f);
        if (e < 5) *dst = hold + (hn - mu) * rs * wmh;
    };

    for (int t = 0; t < cS; t += 4) {
#pragma unroll
        for (int j = 0; j < 4; ++j) {
            float4 gA = rgA[j]; float hoA = rhA[j];
            float4 gB = rgB[j]; float hoB = rhB[j];
            int tp = t + j + 4;              // overreads past t=255 land in ws slack
            rgA[j] = gpA[(size_t)tp * 5120]; rhA[j] = hbA[(size_t)tp * 40];
            rgB[j] = gpB[(size_t)tp * 5120]; rhB[j] = hbB[(size_t)tp * 40];
            step(gA, hoA, hbA + (size_t)(t + j) * 40, cA, nA, mA, a0, a1, a2, a3, a4);
            step(gB, hoB, hbB + (size_t)(t + j) * 40, cB, nB, mB, b0, b1, b2, b3, b4);
        }
    }
}

// ---------------- FFN: fused LN + up-proj + exact GELU gate ----------------
__global__ __launch_bounds__(256) void ff1_k(const float* __restrict__ h, const float* __restrict__ lnw,
                                             const float* __restrict__ upw, float* __restrict__ ff) {
    __shared__ float lnr[4][cE];
    int row0 = blockIdx.x * 4;
    int tid = threadIdx.x;
    if (tid < 4) {
        const float* r = h + (size_t)(row0 + tid) * cE;
        float mu = 0;
        for (int k = 0; k < cE; ++k) mu += r[k];
        mu *= (1.f / cE);
        float va = 0;
        for (int k = 0; k < cE; ++k) { float d = r[k] - mu; va += d * d; }
        va *= (1.f / cE);
        float rs = rsqrtf(va + 1e-5f);
        for (int k = 0; k < cE; ++k) lnr[tid][k] = (r[k] - mu) * rs * lnw[k];
    }
    __syncthreads();
    int r = tid >> 6, f = tid & 63;
    float a = 0, u = 0;
    for (int k = 0; k < cE; ++k) {
        float xv = lnr[r][k];
        a += xv * upw[f * cE + k];
        u += xv * upw[(64 + f) * cE + k];
    }
    float g = 0.5f * a * (1.f + erff(a * 0.70710678118f));
    ff[(size_t)(row0 + r) * 64 + f] = g * u;
}

__global__ __launch_bounds__(320) void ff2_k(const float* __restrict__ ff, const float* __restrict__ dw,
                                             float* __restrict__ h) {
    __shared__ float fl[8 * 64];
    int row0 = blockIdx.x * 8;
    for (int i = threadIdx.x; i < 512; i += 320) fl[i] = ff[(size_t)row0 * 64 + i];
    __syncthreads();
    int r = threadIdx.x / 40, e = threadIdx.x % 40;
    const float* dr = dw + e * 64;
    const float* fr = fl + r * 64;
    float acc = 0.f;
    for (int i = 0; i < 64; ++i) acc += fr[i] * dr[i];
    h[(size_t)(row0 + r) * cE + e] += acc;
}

// ---------------- final LN + out projection ----------------
__global__ __launch_bounds__(256) void final_k(const float* __restrict__ h, const float* __restrict__ lnw,
                                               const float* __restrict__ ow, const float* __restrict__ ob,
                                               float* __restrict__ out) {
    int rid = blockIdx.x * 256 + threadIdx.x;
    const float* r = h + (size_t)rid * cE;
    float mu = 0;
    for (int k = 0; k < cE; ++k) mu += r[k];
    mu *= (1.f / cE);
    float va = 0;
    for (int k = 0; k < cE; ++k) { float d = r[k] - mu; va += d * d; }
    va *= (1.f / cE);
    float rs = rsqrtf(va + 1e-5f);
    float acc = ob[0];
    for (int k = 0; k < cE; ++k) acc += (r[k] - mu) * rs * lnw[k] * ow[k];
    out[rid] = acc;
}

extern "C" void kernel_launch(void* const* d_in, const int* in_sizes, int n_in,
                              void* d_out, int out_size, void* d_ws, size_t ws_size,
                              hipStream_t stream) {
    const float* x        = (const float*)d_in[0];
    const float* in_w     = (const float*)d_in[1];
    const float* in_b     = (const float*)d_in[2];
    const float* m_ln_w   = (const float*)d_in[3];
    const float* m_up_w   = (const float*)d_in[4];
    const float* m_conv_w = (const float*)d_in[5];
    const float* m_conv_b = (const float*)d_in[6];
    const float* m_q_w    = (const float*)d_in[7];
    const float* m_k_w    = (const float*)d_in[8];
    const float* m_v_w    = (const float*)d_in[9];
    const float* m_ig_w   = (const float*)d_in[10];
    const float* m_ig_b   = (const float*)d_in[11];
    const float* m_fg_w   = (const float*)d_in[12];
    const float* m_fg_b   = (const float*)d_in[13];
    const float* m_mhn_w  = (const float*)d_in[14];
    const float* m_skip   = (const float*)d_in[15];
    const float* m_down_w = (const float*)d_in[16];
    const float* s_ln1_w  = (const float*)d_in[17];
    const float* s_conv_w = (const float*)d_in[18];
    const float* s_conv_b = (const float*)d_in[19];
    const float* s_wi     = (const float*)d_in[20];
    const float* s_wf     = (const float*)d_in[21];
    const float* s_wz     = (const float*)d_in[22];
    const float* s_wo     = (const float*)d_in[23];
    const float* s_R      = (const float*)d_in[24];
    const float* s_bias   = (const float*)d_in[25];
    const float* s_mhn_w  = (const float*)d_in[26];
    const float* s_ln2_w  = (const float*)d_in[27];
    const float* s_ff_up  = (const float*)d_in[28];
    const float* s_ff_dn  = (const float*)d_in[29];
    const float* post_ln_w= (const float*)d_in[30];
    const float* out_w    = (const float*)d_in[31];
    const float* out_b    = (const float*)d_in[32];

    float* ws   = (float*)d_ws;
    float* h    = ws;                     // 1,310,720
    float* xmz  = h + 1310720;            // 8,388,608
    float* xc   = xmz + 8388608;          // 4,194,304
    float* qb   = xc + 4194304;           // 4,194,304
    float* kb   = qb + 4194304;           // 4,194,304
    float* vb   = kb + 4194304;           // 4,194,304
    float* ipb  = vb + 4194304;           //   262,144
    float* fpb  = ipb + 262144;           //   262,144
    float* hatt = fpb + 262144;           // 4,194,304   (~119 MB total)
    // slstm / ff aliases into the xmz region (dead at those points)
    float* lnbuf = xmz;                   // 1,310,720
    float* xcs   = xmz + 1310720;         // 1,310,720
    float* gall  = xmz + 2621440;         // 5,242,880 (+ scan overreads into tail slack)
    float* ffbuf = xmz;                   // 2,097,152

    init_k<<<5120, 256, 0, stream>>>(x, in_w, in_b, h);

    auto mlstm = [&](int j) {
        ln_up_k<<<4096, 256, 0, stream>>>(h, m_ln_w + j * cE, m_up_w + (size_t)j * 256 * cE, xmz);
        conv_silu_k<128><<<16384, 256, 0, stream>>>(xmz, 256, m_conv_w + j * cI * cK, m_conv_b + j * cI, xc);
        qkv_k<<<16384, 256, 0, stream>>>(xc, xmz, m_q_w + j * 512, m_k_w + j * 512, m_v_w + j * 512, qb, kb, vb);
        gates_k<<<1024, 128, 0, stream>>>(qb, kb, vb, m_ig_w + j * cNH * 384, m_ig_b + j * cNH,
                                          m_fg_w + j * cNH * 384, m_fg_b + j * cNH, ipb, fpb);
        attn_k<<<1024, 128, 0, stream>>>(qb, kb, vb, ipb, fpb, hatt);
        mhn_y_k<<<1024, 256, 0, stream>>>(hatt, xc, xmz, m_mhn_w + j * cI, m_skip + j * cI);
        down_res_k<<<4096, 320, 0, stream>>>(hatt, m_down_w + j * cE * cI, h);
    };

    mlstm(0);

    ln_rows_k<<<128, 256, 0, stream>>>(h, s_ln1_w, lnbuf);
    conv_silu_k<40><<<5120, 256, 0, stream>>>(lnbuf, 40, s_conv_w, s_conv_b, xcs);
    sgates_k<<<20480, 256, 0, stream>>>(xcs, lnbuf, s_wi, s_wf, s_wz, s_wo, gall);
    scan_k<<<64, 64, 0, stream>>>(gall, s_R, s_bias, s_mhn_w, h);

    ff1_k<<<8192, 256, 0, stream>>>(h, s_ln2_w, s_ff_up, ffbuf);
    ff2_k<<<4096, 320, 0, stream>>>(ffbuf, s_ff_dn, h);

    mlstm(1);
    mlstm(2);

    final_k<<<128, 256, 0, stream>>>(h, post_ln_w, out_w, out_b, (float*)d_out);
}